// Round 1
// baseline (813.077 us; speedup 1.0000x reference)
//
#include <hip/hip_runtime.h>
#include <math.h>

#define RR 128          // spatial resolution (grid_space + features)
#define TT 150          // time resolution
#define NCH 48          // RANK*OUT_DIM*TIME_RANK
#define NF 32           // feature channels

// one block per ray; blockDim.x == 128 samples per ray (2 waves)
__global__ __launch_bounds__(128) void lrv_kernel(
    const float* __restrict__ rays_d,
    const float* __restrict__ pts,
    const float* __restrict__ times,
    const float* __restrict__ deltas,
    const float* __restrict__ bg,
    const float* __restrict__ gspace,   // [3][48][RR][RR]
    const float* __restrict__ gtime,    // [12][TT]
    const float* __restrict__ feat,     // [NF][RR][RR][RR]
    const float* __restrict__ W1, const float* __restrict__ b1,   // [35][64],[64]
    const float* __restrict__ W2, const float* __restrict__ b2,   // [64][16],[16]
    const float* __restrict__ Wc1, const float* __restrict__ bc1, // [18][64],[64]
    const float* __restrict__ Wc2, const float* __restrict__ bc2, // [64][3],[3]
    const int*  __restrict__ ridx,
    float* __restrict__ out)
{
    // ---- LDS staging (weights are wave-uniform -> broadcast reads) ----
    __shared__ __align__(16) float4 sW1v[35 * 16];   // [i][j/4]
    __shared__ __align__(16) float4 sW2v[64 * 4];    // [j][k/4]
    __shared__ __align__(16) float4 sWc1v[18 * 16];  // [i][j/4]
    __shared__ __align__(16) float  sWc2[64 * 3];
    __shared__ float sb1[64], sbc1[64], sb2[16], sbc2[4];
    __shared__ float sGT[12 * TT];
    __shared__ float waveTot[2];
    __shared__ float4 rbuf[2];

    const int tid  = threadIdx.x;
    const int lane = tid & 63;

    {
        float* w1 = (float*)sW1v;
        for (int k = tid; k < 35 * 64; k += 128) w1[k] = W1[k];
        float* w2 = (float*)sW2v;
        for (int k = tid; k < 64 * 16; k += 128) w2[k] = W2[k];
        float* wc1 = (float*)sWc1v;
        for (int k = tid; k < 18 * 64; k += 128) wc1[k] = Wc1[k];
        for (int k = tid; k < 64 * 3; k += 128) sWc2[k] = Wc2[k];
        if (tid < 64) { sb1[tid] = b1[tid]; sbc1[tid] = bc1[tid]; }
        if (tid < 16) sb2[tid] = b2[tid];
        if (tid < 3)  sbc2[tid] = bc2[tid];
        for (int k = tid; k < 12 * TT; k += 128) sGT[k] = gtime[k];
    }
    __syncthreads();

    const int ray = blockIdx.x;
    const int i   = ray * 128 + tid;

    // ---- 1D time grid sample -> it[3][4] ----
    float itv[12];
    {
        float t = times[i];
        float x = (t + 1.f) * 0.5f * (float)(TT - 1);
        x = fminf(fmaxf(x, 0.f), (float)(TT - 1));
        int ti0 = (int)floorf(x);
        ti0 = min(max(ti0, 0), TT - 2);
        float tw = x - (float)ti0;
        #pragma unroll
        for (int c = 0; c < 12; c++) {
            float v0 = sGT[c * TT + ti0];
            float v1 = sGT[c * TT + ti0 + 1];
            itv[c] = v0 * (1.f - tw) + v1 * tw;
        }
    }

    // ---- 3 plane bilinear samples, low-rank contraction ----
    float p0 = pts[i * 3 + 0], p1 = pts[i * 3 + 1], p2 = pts[i * 3 + 2];
    int   pbase[3];
    float pw[3][4];
    {
        const float pa[3] = { p0, p0, p1 };
        const float pb[3] = { p1, p2, p2 };
        #pragma unroll
        for (int c = 0; c < 3; c++) {
            float xa = fminf(fmaxf((pa[c] + 1.f) * 0.5f * (float)(RR - 1), 0.f), (float)(RR - 1));
            float xb = fminf(fmaxf((pb[c] + 1.f) * 0.5f * (float)(RR - 1), 0.f), (float)(RR - 1));
            int ia = min(max((int)floorf(xa), 0), RR - 2);
            int ib = min(max((int)floorf(xb), 0), RR - 2);
            float wa = xa - (float)ia, wb = xb - (float)ib;
            pbase[c] = ia * RR + ib;
            pw[c][0] = (1.f - wa) * (1.f - wb);
            pw[c][1] = (1.f - wa) * wb;
            pw[c][2] = wa * (1.f - wb);
            pw[c][3] = wa * wb;
        }
    }
    float S12[12];
    #pragma unroll
    for (int k = 0; k < 12; k++) S12[k] = 0.f;
    #pragma unroll 4
    for (int ch = 0; ch < NCH; ch++) {
        float prod = 1.f;
        #pragma unroll
        for (int c = 0; c < 3; c++) {
            const float* g = gspace + (size_t)(c * NCH + ch) * (RR * RR) + pbase[c];
            float v = pw[c][0] * g[0] + pw[c][1] * g[1]
                    + pw[c][2] * g[RR] + pw[c][3] * g[RR + 1];
            prod *= v;
        }
        S12[ch >> 2] += prod;
    }
    float cc[3];
    #pragma unroll
    for (int o = 0; o < 3; o++) {
        float a = 0.f;
        #pragma unroll
        for (int t = 0; t < 4; t++) a += S12[o * 4 + t] * itv[o * 4 + t];
        cc[o] = fminf(fmaxf(a, -1.f), 1.f);
    }

    // ---- 3D feature trilinear sample ----
    float in35[35];
    {
        int   fi[3];
        float fw[3];
        #pragma unroll
        for (int k = 0; k < 3; k++) {
            float xk = fminf(fmaxf((cc[k] + 1.f) * 0.5f * (float)(RR - 1), 0.f), (float)(RR - 1));
            int ik = min(max((int)floorf(xk), 0), RR - 2);
            fi[k] = ik; fw[k] = xk - (float)ik;
        }
        float w0 = fw[0], w1 = fw[1], w2 = fw[2];
        float cw0 = (1.f - w0) * (1.f - w1) * (1.f - w2);
        float cw1 = (1.f - w0) * (1.f - w1) * w2;
        float cw2 = (1.f - w0) * w1 * (1.f - w2);
        float cw3 = (1.f - w0) * w1 * w2;
        float cw4 = w0 * (1.f - w1) * (1.f - w2);
        float cw5 = w0 * (1.f - w1) * w2;
        float cw6 = w0 * w1 * (1.f - w2);
        float cw7 = w0 * w1 * w2;
        size_t fb = ((size_t)fi[0] * RR + fi[1]) * RR + fi[2];
        #pragma unroll 4
        for (int ch = 0; ch < NF; ch++) {
            const float* f = feat + (size_t)ch * (RR * RR * RR) + fb;
            float v = cw0 * f[0]            + cw1 * f[1]
                    + cw2 * f[RR]           + cw3 * f[RR + 1]
                    + cw4 * f[RR * RR]      + cw5 * f[RR * RR + 1]
                    + cw6 * f[RR * RR + RR] + cw7 * f[RR * RR + RR + 1];
            in35[ch] = v;
        }
    }
    // ray direction (normalized)
    {
        int r = ridx[i];
        float d0 = rays_d[r * 3 + 0], d1 = rays_d[r * 3 + 1], d2 = rays_d[r * 3 + 2];
        float inv = 1.f / sqrtf(d0 * d0 + d1 * d1 + d2 * d2);
        in35[32] = d0 * inv; in35[33] = d1 * inv; in35[34] = d2 * inv;
    }

    // ---- MLP: (35 -> 64 relu -> 16), fused ----
    float sacc[16];
    #pragma unroll
    for (int k = 0; k < 16; k++) sacc[k] = sb2[k];
    #pragma unroll 2
    for (int jb = 0; jb < 16; jb++) {             // 4 hidden units at a time
        float a0 = sb1[jb * 4 + 0], a1 = sb1[jb * 4 + 1];
        float a2 = sb1[jb * 4 + 2], a3 = sb1[jb * 4 + 3];
        #pragma unroll
        for (int ii = 0; ii < 35; ii++) {
            float xv = in35[ii];
            float4 wv = sW1v[ii * 16 + jb];
            a0 = fmaf(xv, wv.x, a0); a1 = fmaf(xv, wv.y, a1);
            a2 = fmaf(xv, wv.z, a2); a3 = fmaf(xv, wv.w, a3);
        }
        a0 = fmaxf(a0, 0.f); a1 = fmaxf(a1, 0.f);
        a2 = fmaxf(a2, 0.f); a3 = fmaxf(a3, 0.f);
        #pragma unroll
        for (int kg = 0; kg < 4; kg++) {
            float4 r0 = sW2v[(jb * 4 + 0) * 4 + kg];
            float4 r1 = sW2v[(jb * 4 + 1) * 4 + kg];
            float4 r2 = sW2v[(jb * 4 + 2) * 4 + kg];
            float4 r3 = sW2v[(jb * 4 + 3) * 4 + kg];
            sacc[kg * 4 + 0] += a0 * r0.x + a1 * r1.x + a2 * r2.x + a3 * r3.x;
            sacc[kg * 4 + 1] += a0 * r0.y + a1 * r1.y + a2 * r2.y + a3 * r3.y;
            sacc[kg * 4 + 2] += a0 * r0.z + a1 * r1.z + a2 * r2.z + a3 * r3.z;
            sacc[kg * 4 + 3] += a0 * r0.w + a1 * r1.w + a2 * r2.w + a3 * r3.w;
        }
    }
    float sigma = expf(fminf(fmaxf(sacc[0], -15.f), 15.f));

    // ---- color MLP: (15+3 -> 64 relu -> 3), fused ----
    float in18[18];
    #pragma unroll
    for (int k = 0; k < 15; k++) in18[k] = sacc[k + 1];
    in18[15] = in35[32]; in18[16] = in35[33]; in18[17] = in35[34];
    float rc0 = sbc2[0], rc1 = sbc2[1], rc2 = sbc2[2];
    #pragma unroll 2
    for (int jb = 0; jb < 16; jb++) {
        float a0 = sbc1[jb * 4 + 0], a1 = sbc1[jb * 4 + 1];
        float a2 = sbc1[jb * 4 + 2], a3 = sbc1[jb * 4 + 3];
        #pragma unroll
        for (int ii = 0; ii < 18; ii++) {
            float xv = in18[ii];
            float4 wv = sWc1v[ii * 16 + jb];
            a0 = fmaf(xv, wv.x, a0); a1 = fmaf(xv, wv.y, a1);
            a2 = fmaf(xv, wv.z, a2); a3 = fmaf(xv, wv.w, a3);
        }
        a0 = fmaxf(a0, 0.f); a1 = fmaxf(a1, 0.f);
        a2 = fmaxf(a2, 0.f); a3 = fmaxf(a3, 0.f);
        rc0 += a0 * sWc2[(jb * 4 + 0) * 3 + 0] + a1 * sWc2[(jb * 4 + 1) * 3 + 0]
             + a2 * sWc2[(jb * 4 + 2) * 3 + 0] + a3 * sWc2[(jb * 4 + 3) * 3 + 0];
        rc1 += a0 * sWc2[(jb * 4 + 0) * 3 + 1] + a1 * sWc2[(jb * 4 + 1) * 3 + 1]
             + a2 * sWc2[(jb * 4 + 2) * 3 + 1] + a3 * sWc2[(jb * 4 + 3) * 3 + 1];
        rc2 += a0 * sWc2[(jb * 4 + 0) * 3 + 2] + a1 * sWc2[(jb * 4 + 1) * 3 + 2]
             + a2 * sWc2[(jb * 4 + 2) * 3 + 2] + a3 * sWc2[(jb * 4 + 3) * 3 + 2];
    }
    float r_ = 1.f / (1.f + expf(-rc0));
    float g_ = 1.f / (1.f + expf(-rc1));
    float b_ = 1.f / (1.f + expf(-rc2));

    // ---- per-ray compositing: exclusive scan of tau over 128 samples ----
    float tau = sigma * deltas[i];
    float v = tau;
    #pragma unroll
    for (int off = 1; off < 64; off <<= 1) {
        float u = __shfl_up(v, off, 64);
        if (lane >= off) v += u;
    }
    if (lane == 63) waveTot[tid >> 6] = v;
    float excl = v - tau;
    __syncthreads();
    if (tid >= 64) excl += waveTot[0];

    float Tr = expf(-excl);
    float w  = Tr * (1.f - expf(-tau));

    float ax = w * r_, ay = w * g_, az = w * b_, aw = w;
    #pragma unroll
    for (int off = 32; off; off >>= 1) {
        ax += __shfl_down(ax, off, 64);
        ay += __shfl_down(ay, off, 64);
        az += __shfl_down(az, off, 64);
        aw += __shfl_down(aw, off, 64);
    }
    if (lane == 0) rbuf[tid >> 6] = make_float4(ax, ay, az, aw);
    __syncthreads();
    if (tid == 0) {
        float cx = rbuf[0].x + rbuf[1].x;
        float cy = rbuf[0].y + rbuf[1].y;
        float cz = rbuf[0].z + rbuf[1].z;
        float alpha = rbuf[0].w + rbuf[1].w;
        out[ray * 3 + 0] = cx + (1.f - alpha) * bg[ray * 3 + 0];
        out[ray * 3 + 1] = cy + (1.f - alpha) * bg[ray * 3 + 1];
        out[ray * 3 + 2] = cz + (1.f - alpha) * bg[ray * 3 + 2];
    }
}

extern "C" void kernel_launch(void* const* d_in, const int* in_sizes, int n_in,
                              void* d_out, int out_size, void* d_ws, size_t ws_size,
                              hipStream_t stream) {
    const float* rays_d = (const float*)d_in[0];
    const float* pts    = (const float*)d_in[1];
    const float* times  = (const float*)d_in[2];
    const float* deltas = (const float*)d_in[3];
    const float* bg     = (const float*)d_in[4];
    const float* gspace = (const float*)d_in[5];
    const float* gtime  = (const float*)d_in[6];
    const float* feat   = (const float*)d_in[7];
    const float* W1  = (const float*)d_in[8];
    const float* b1  = (const float*)d_in[9];
    const float* W2  = (const float*)d_in[10];
    const float* b2  = (const float*)d_in[11];
    const float* Wc1 = (const float*)d_in[12];
    const float* bc1 = (const float*)d_in[13];
    const float* Wc2 = (const float*)d_in[14];
    const float* bc2 = (const float*)d_in[15];
    const int*   ridx = (const int*)d_in[16];

    const int n_rays = in_sizes[0] / 3;
    const int N      = in_sizes[2];
    const int S      = N / n_rays;   // 128

    lrv_kernel<<<dim3(n_rays), dim3(S), 0, stream>>>(
        rays_d, pts, times, deltas, bg, gspace, gtime, feat,
        W1, b1, W2, b2, Wc1, bc1, Wc2, bc2, ridx, (float*)d_out);
}

// Round 2
// 520.923 us; speedup vs baseline: 1.5608x; 1.5608x over previous
//
#include <hip/hip_runtime.h>
#include <math.h>

#define RR 128          // spatial resolution (grid_space + features)
#define TT 150          // time resolution
#define NCH 48          // RANK*OUT_DIM*TIME_RANK
#define NF 32           // feature channels

__device__ __forceinline__ float4 ld4(const float* p) {
    return *reinterpret_cast<const float4*>(p);
}
__device__ __forceinline__ float4 fma4(float s, float4 v, float4 a) {
    a.x = fmaf(s, v.x, a.x); a.y = fmaf(s, v.y, a.y);
    a.z = fmaf(s, v.z, a.z); a.w = fmaf(s, v.w, a.w);
    return a;
}
__device__ __forceinline__ float4 mul4s(float4 v, float s) {
    v.x *= s; v.y *= s; v.z *= s; v.w *= s; return v;
}
__device__ __forceinline__ float4 mul4(float4 a, float4 b) {
    a.x *= b.x; a.y *= b.y; a.z *= b.z; a.w *= b.w; return a;
}

// bilinear over 4 corners of one plane, 4 channels at a time
__device__ __forceinline__ float4 bil4(const float* __restrict__ g,
                                       const size_t* b, int cb,
                                       const float* w) {
    float4 r = mul4s(ld4(g + b[0] + cb * 4), w[0]);
    r = fma4(w[1], ld4(g + b[1] + cb * 4), r);
    r = fma4(w[2], ld4(g + b[2] + cb * 4), r);
    r = fma4(w[3], ld4(g + b[3] + cb * 4), r);
    return r;
}

// ---- transpose features [32][V] -> [V][32], V = 128^3 ----
__global__ __launch_bounds__(256) void tfeat(const float* __restrict__ in,
                                             float* __restrict__ out) {
    __shared__ float lds[32][65];
    const int t = threadIdx.x;
    const size_t V = (size_t)RR * RR * RR;
    const size_t v0 = (size_t)blockIdx.x * 64;
    #pragma unroll
    for (int k = 0; k < 8; k++) {
        int idx = k * 256 + t; int c = idx >> 6; int vv = idx & 63;
        lds[c][vv] = in[(size_t)c * V + v0 + vv];
    }
    __syncthreads();
    #pragma unroll
    for (int k = 0; k < 8; k++) {
        int idx = k * 256 + t; int vv = idx >> 5; int c = idx & 31;
        out[(v0 + vv) * 32 + c] = lds[c][vv];
    }
}

// ---- transpose grid_space [3][48][16384] -> [3][16384][48] ----
__global__ __launch_bounds__(256) void tgsp(const float* __restrict__ in,
                                            float* __restrict__ out) {
    __shared__ float lds[48][65];
    const int t = threadIdx.x;
    const int p = blockIdx.x >> 8;          // plane
    const int tile = blockIdx.x & 255;
    const size_t V = (size_t)RR * RR;       // 16384
    const size_t v0 = (size_t)tile * 64;
    const float* ip = in + (size_t)p * NCH * V;
    float* op = out + (size_t)p * V * NCH;
    #pragma unroll
    for (int k = 0; k < 12; k++) {
        int idx = k * 256 + t; int c = idx >> 6; int vv = idx & 63;
        lds[c][vv] = ip[(size_t)c * V + v0 + vv];
    }
    __syncthreads();
    #pragma unroll
    for (int k = 0; k < 12; k++) {
        int idx = k * 256 + t; int vv = idx / 48; int c = idx - vv * 48;
        op[(v0 + vv) * NCH + c] = lds[c][vv];
    }
}

// ---- main kernel: 2 rays per block (256 threads = 4 waves) ----
// TR=true: gspace is [3][R][R][48], feat is [R][R][R][32] (transposed)
template<bool TR>
__global__ __launch_bounds__(256, 5) void lrv_main(
    const float* __restrict__ rays_d,
    const float* __restrict__ pts,
    const float* __restrict__ times,
    const float* __restrict__ deltas,
    const float* __restrict__ bg,
    const float* __restrict__ gspace,
    const float* __restrict__ gtime,    // [12][TT] original layout
    const float* __restrict__ feat,
    const float* __restrict__ W1, const float* __restrict__ b1,
    const float* __restrict__ W2, const float* __restrict__ b2,
    const float* __restrict__ Wc1, const float* __restrict__ bc1,
    const float* __restrict__ Wc2, const float* __restrict__ bc2,
    const int*  __restrict__ ridx,
    float* __restrict__ out)
{
    __shared__ __align__(16) float4 sW1v[35 * 16];   // [i][j/4]
    __shared__ __align__(16) float4 sW2v[64 * 4];    // [j][k/4]
    __shared__ __align__(16) float4 sWc1v[18 * 16];  // [i][j/4]
    __shared__ __align__(16) float  sWc2[64 * 3];
    __shared__ float sb1[64], sbc1[64], sb2[16], sbc2[4];
    __shared__ float sGT[12 * TT];
    __shared__ float waveTot[4];
    __shared__ float4 rbuf[4];

    const int tid  = threadIdx.x;
    const int lane = tid & 63;
    const int wv   = tid >> 6;          // wave in block, 0..3

    {
        float* w1 = (float*)sW1v;
        for (int k = tid; k < 35 * 64; k += 256) w1[k] = W1[k];
        float* w2 = (float*)sW2v;
        for (int k = tid; k < 64 * 16; k += 256) w2[k] = W2[k];
        float* wc1 = (float*)sWc1v;
        for (int k = tid; k < 18 * 64; k += 256) wc1[k] = Wc1[k];
        for (int k = tid; k < 64 * 3; k += 256) sWc2[k] = Wc2[k];
        if (tid < 64) { sb1[tid] = b1[tid]; sbc1[tid] = bc1[tid]; }
        if (tid < 16) sb2[tid] = b2[tid];
        if (tid < 3)  sbc2[tid] = bc2[tid];
        for (int k = tid; k < 12 * TT; k += 256) sGT[k] = gtime[k];
    }
    __syncthreads();

    const int ray = blockIdx.x * 2 + (tid >> 7);
    const int i   = ray * 128 + (tid & 127);

    // ---- 1D time grid sample -> itv[12] ----
    float itv[12];
    {
        float t = times[i];
        float x = (t + 1.f) * 0.5f * (float)(TT - 1);
        x = fminf(fmaxf(x, 0.f), (float)(TT - 1));
        int ti0 = (int)floorf(x);
        ti0 = min(max(ti0, 0), TT - 2);
        float tw = x - (float)ti0;
        #pragma unroll
        for (int c = 0; c < 12; c++) {
            float v0 = sGT[c * TT + ti0];
            float v1 = sGT[c * TT + ti0 + 1];
            itv[c] = v0 * (1.f - tw) + v1 * tw;
        }
    }

    // ---- 3 plane bilinear samples, low-rank contraction ----
    float p0 = pts[i * 3 + 0], p1 = pts[i * 3 + 1], p2 = pts[i * 3 + 2];
    int   pbia[3], pbib[3];
    float pw[3][4];
    {
        const float pa[3] = { p0, p0, p1 };
        const float pb[3] = { p1, p2, p2 };
        #pragma unroll
        for (int c = 0; c < 3; c++) {
            float xa = fminf(fmaxf((pa[c] + 1.f) * 0.5f * (float)(RR - 1), 0.f), (float)(RR - 1));
            float xb = fminf(fmaxf((pb[c] + 1.f) * 0.5f * (float)(RR - 1), 0.f), (float)(RR - 1));
            int ia = min(max((int)floorf(xa), 0), RR - 2);
            int ib = min(max((int)floorf(xb), 0), RR - 2);
            float wa = xa - (float)ia, wb = xb - (float)ib;
            pbia[c] = ia; pbib[c] = ib;
            pw[c][0] = (1.f - wa) * (1.f - wb);
            pw[c][1] = (1.f - wa) * wb;
            pw[c][2] = wa * (1.f - wb);
            pw[c][3] = wa * wb;
        }
    }
    float S12[12];
    if constexpr (TR) {
        // gspace: [3][RR][RR][48]
        size_t b[3][4];
        #pragma unroll
        for (int c = 0; c < 3; c++) {
            size_t b00 = (size_t)c * (RR * RR * NCH)
                       + ((size_t)pbia[c] * RR + pbib[c]) * NCH;
            b[c][0] = b00; b[c][1] = b00 + NCH;
            b[c][2] = b00 + (size_t)RR * NCH; b[c][3] = b00 + (size_t)RR * NCH + NCH;
        }
        #pragma unroll 2
        for (int cb = 0; cb < 12; cb++) {
            float4 v = bil4(gspace, b[0], cb, pw[0]);
            v = mul4(v, bil4(gspace, b[1], cb, pw[1]));
            v = mul4(v, bil4(gspace, b[2], cb, pw[2]));
            S12[cb] = v.x + v.y + v.z + v.w;
        }
    } else {
        #pragma unroll
        for (int k = 0; k < 12; k++) S12[k] = 0.f;
        #pragma unroll 4
        for (int ch = 0; ch < NCH; ch++) {
            float prod = 1.f;
            #pragma unroll
            for (int c = 0; c < 3; c++) {
                const float* g = gspace + (size_t)(c * NCH + ch) * (RR * RR)
                               + pbia[c] * RR + pbib[c];
                float v = pw[c][0] * g[0] + pw[c][1] * g[1]
                        + pw[c][2] * g[RR] + pw[c][3] * g[RR + 1];
                prod *= v;
            }
            S12[ch >> 2] += prod;
        }
    }
    float cc[3];
    #pragma unroll
    for (int o = 0; o < 3; o++) {
        float a = 0.f;
        #pragma unroll
        for (int t = 0; t < 4; t++) a += S12[o * 4 + t] * itv[o * 4 + t];
        cc[o] = fminf(fmaxf(a, -1.f), 1.f);
    }

    // ---- 3D feature trilinear sample ----
    __align__(16) float in35[36];
    {
        int   fi[3];
        float fw[3];
        #pragma unroll
        for (int k = 0; k < 3; k++) {
            float xk = fminf(fmaxf((cc[k] + 1.f) * 0.5f * (float)(RR - 1), 0.f), (float)(RR - 1));
            int ik = min(max((int)floorf(xk), 0), RR - 2);
            fi[k] = ik; fw[k] = xk - (float)ik;
        }
        float w0 = fw[0], w1 = fw[1], w2 = fw[2];
        float cw[8];
        cw[0] = (1.f - w0) * (1.f - w1) * (1.f - w2);
        cw[1] = (1.f - w0) * (1.f - w1) * w2;
        cw[2] = (1.f - w0) * w1 * (1.f - w2);
        cw[3] = (1.f - w0) * w1 * w2;
        cw[4] = w0 * (1.f - w1) * (1.f - w2);
        cw[5] = w0 * (1.f - w1) * w2;
        cw[6] = w0 * w1 * (1.f - w2);
        cw[7] = w0 * w1 * w2;
        if constexpr (TR) {
            // feat: [RR][RR][RR][32]
            float4* in4 = reinterpret_cast<float4*>(in35);
            #pragma unroll
            for (int q = 0; q < 8; q++) in4[q] = make_float4(0.f, 0.f, 0.f, 0.f);
            const size_t oz = NF, oy = (size_t)RR * NF, ox = (size_t)RR * RR * NF;
            const size_t fb = (((size_t)fi[0] * RR + fi[1]) * RR + fi[2]) * NF;
            const size_t coff[8] = { 0, oz, oy, oy + oz, ox, ox + oz, ox + oy, ox + oy + oz };
            #pragma unroll
            for (int corner = 0; corner < 8; corner++) {
                const float* fp = feat + fb + coff[corner];
                const float s = cw[corner];
                #pragma unroll
                for (int q = 0; q < 8; q++)
                    in4[q] = fma4(s, ld4(fp + q * 4), in4[q]);
            }
        } else {
            size_t fb = ((size_t)fi[0] * RR + fi[1]) * RR + fi[2];
            #pragma unroll 4
            for (int ch = 0; ch < NF; ch++) {
                const float* f = feat + (size_t)ch * (RR * RR * RR) + fb;
                in35[ch] = cw[0] * f[0]            + cw[1] * f[1]
                         + cw[2] * f[RR]           + cw[3] * f[RR + 1]
                         + cw[4] * f[RR * RR]      + cw[5] * f[RR * RR + 1]
                         + cw[6] * f[RR * RR + RR] + cw[7] * f[RR * RR + RR + 1];
            }
        }
    }
    // ray direction (normalized)
    {
        int r = ridx[i];
        float d0 = rays_d[r * 3 + 0], d1 = rays_d[r * 3 + 1], d2 = rays_d[r * 3 + 2];
        float inv = 1.f / sqrtf(d0 * d0 + d1 * d1 + d2 * d2);
        in35[32] = d0 * inv; in35[33] = d1 * inv; in35[34] = d2 * inv;
    }

    // ---- MLP: (35 -> 64 relu -> 16), fused ----
    float sacc[16];
    #pragma unroll
    for (int k = 0; k < 16; k++) sacc[k] = sb2[k];
    #pragma unroll 2
    for (int jb = 0; jb < 16; jb++) {
        float a0 = sb1[jb * 4 + 0], a1 = sb1[jb * 4 + 1];
        float a2 = sb1[jb * 4 + 2], a3 = sb1[jb * 4 + 3];
        #pragma unroll
        for (int ii = 0; ii < 35; ii++) {
            float xv = in35[ii];
            float4 wvv = sW1v[ii * 16 + jb];
            a0 = fmaf(xv, wvv.x, a0); a1 = fmaf(xv, wvv.y, a1);
            a2 = fmaf(xv, wvv.z, a2); a3 = fmaf(xv, wvv.w, a3);
        }
        a0 = fmaxf(a0, 0.f); a1 = fmaxf(a1, 0.f);
        a2 = fmaxf(a2, 0.f); a3 = fmaxf(a3, 0.f);
        #pragma unroll
        for (int kg = 0; kg < 4; kg++) {
            float4 r0 = sW2v[(jb * 4 + 0) * 4 + kg];
            float4 r1 = sW2v[(jb * 4 + 1) * 4 + kg];
            float4 r2 = sW2v[(jb * 4 + 2) * 4 + kg];
            float4 r3 = sW2v[(jb * 4 + 3) * 4 + kg];
            sacc[kg * 4 + 0] += a0 * r0.x + a1 * r1.x + a2 * r2.x + a3 * r3.x;
            sacc[kg * 4 + 1] += a0 * r0.y + a1 * r1.y + a2 * r2.y + a3 * r3.y;
            sacc[kg * 4 + 2] += a0 * r0.z + a1 * r1.z + a2 * r2.z + a3 * r3.z;
            sacc[kg * 4 + 3] += a0 * r0.w + a1 * r1.w + a2 * r2.w + a3 * r3.w;
        }
    }
    float sigma = expf(fminf(fmaxf(sacc[0], -15.f), 15.f));

    // ---- color MLP: (15+3 -> 64 relu -> 3), fused ----
    float in18[18];
    #pragma unroll
    for (int k = 0; k < 15; k++) in18[k] = sacc[k + 1];
    in18[15] = in35[32]; in18[16] = in35[33]; in18[17] = in35[34];
    float rc0 = sbc2[0], rc1 = sbc2[1], rc2 = sbc2[2];
    #pragma unroll 2
    for (int jb = 0; jb < 16; jb++) {
        float a0 = sbc1[jb * 4 + 0], a1 = sbc1[jb * 4 + 1];
        float a2 = sbc1[jb * 4 + 2], a3 = sbc1[jb * 4 + 3];
        #pragma unroll
        for (int ii = 0; ii < 18; ii++) {
            float xv = in18[ii];
            float4 wvv = sWc1v[ii * 16 + jb];
            a0 = fmaf(xv, wvv.x, a0); a1 = fmaf(xv, wvv.y, a1);
            a2 = fmaf(xv, wvv.z, a2); a3 = fmaf(xv, wvv.w, a3);
        }
        a0 = fmaxf(a0, 0.f); a1 = fmaxf(a1, 0.f);
        a2 = fmaxf(a2, 0.f); a3 = fmaxf(a3, 0.f);
        rc0 += a0 * sWc2[(jb * 4 + 0) * 3 + 0] + a1 * sWc2[(jb * 4 + 1) * 3 + 0]
             + a2 * sWc2[(jb * 4 + 2) * 3 + 0] + a3 * sWc2[(jb * 4 + 3) * 3 + 0];
        rc1 += a0 * sWc2[(jb * 4 + 0) * 3 + 1] + a1 * sWc2[(jb * 4 + 1) * 3 + 1]
             + a2 * sWc2[(jb * 4 + 2) * 3 + 1] + a3 * sWc2[(jb * 4 + 3) * 3 + 1];
        rc2 += a0 * sWc2[(jb * 4 + 0) * 3 + 2] + a1 * sWc2[(jb * 4 + 1) * 3 + 2]
             + a2 * sWc2[(jb * 4 + 2) * 3 + 2] + a3 * sWc2[(jb * 4 + 3) * 3 + 2];
    }
    float r_ = 1.f / (1.f + expf(-rc0));
    float g_ = 1.f / (1.f + expf(-rc1));
    float b_ = 1.f / (1.f + expf(-rc2));

    // ---- per-ray compositing: exclusive scan of tau over 128 samples ----
    float tau = sigma * deltas[i];
    float v = tau;
    #pragma unroll
    for (int off = 1; off < 64; off <<= 1) {
        float u = __shfl_up(v, off, 64);
        if (lane >= off) v += u;
    }
    if (lane == 63) waveTot[wv] = v;
    float excl = v - tau;
    __syncthreads();
    if (wv & 1) excl += waveTot[wv & 2];

    float Tr = expf(-excl);
    float w  = Tr * (1.f - expf(-tau));

    float ax = w * r_, ay = w * g_, az = w * b_, aw = w;
    #pragma unroll
    for (int off = 32; off; off >>= 1) {
        ax += __shfl_down(ax, off, 64);
        ay += __shfl_down(ay, off, 64);
        az += __shfl_down(az, off, 64);
        aw += __shfl_down(aw, off, 64);
    }
    if (lane == 0) rbuf[wv] = make_float4(ax, ay, az, aw);
    __syncthreads();
    if (lane == 0 && (wv & 1) == 0) {
        float cx = rbuf[wv].x + rbuf[wv + 1].x;
        float cy = rbuf[wv].y + rbuf[wv + 1].y;
        float cz = rbuf[wv].z + rbuf[wv + 1].z;
        float alpha = rbuf[wv].w + rbuf[wv + 1].w;
        out[ray * 3 + 0] = cx + (1.f - alpha) * bg[ray * 3 + 0];
        out[ray * 3 + 1] = cy + (1.f - alpha) * bg[ray * 3 + 1];
        out[ray * 3 + 2] = cz + (1.f - alpha) * bg[ray * 3 + 2];
    }
}

extern "C" void kernel_launch(void* const* d_in, const int* in_sizes, int n_in,
                              void* d_out, int out_size, void* d_ws, size_t ws_size,
                              hipStream_t stream) {
    const float* rays_d = (const float*)d_in[0];
    const float* pts    = (const float*)d_in[1];
    const float* times  = (const float*)d_in[2];
    const float* deltas = (const float*)d_in[3];
    const float* bg     = (const float*)d_in[4];
    const float* gspace = (const float*)d_in[5];
    const float* gtime  = (const float*)d_in[6];
    const float* feat   = (const float*)d_in[7];
    const float* W1  = (const float*)d_in[8];
    const float* b1  = (const float*)d_in[9];
    const float* W2  = (const float*)d_in[10];
    const float* b2  = (const float*)d_in[11];
    const float* Wc1 = (const float*)d_in[12];
    const float* bc1 = (const float*)d_in[13];
    const float* Wc2 = (const float*)d_in[14];
    const float* bc2 = (const float*)d_in[15];
    const int*   ridx = (const int*)d_in[16];

    const int n_rays = in_sizes[0] / 3;   // 4096

    const size_t FEAT_B = (size_t)NF * RR * RR * RR * sizeof(float);   // 268 MB
    const size_t GSP_B  = (size_t)3 * NCH * RR * RR * sizeof(float);   // 9.4 MB

    if (ws_size >= FEAT_B + GSP_B) {
        float* feat_t = (float*)d_ws;
        float* gsp_t  = (float*)((char*)d_ws + FEAT_B);
        tfeat<<<dim3(RR * RR * RR / 64), dim3(256), 0, stream>>>(feat, feat_t);
        tgsp<<<dim3(3 * 256), dim3(256), 0, stream>>>(gspace, gsp_t);
        lrv_main<true><<<dim3(n_rays / 2), dim3(256), 0, stream>>>(
            rays_d, pts, times, deltas, bg, gsp_t, gtime, feat_t,
            W1, b1, W2, b2, Wc1, bc1, Wc2, bc2, ridx, (float*)d_out);
    } else {
        lrv_main<false><<<dim3(n_rays / 2), dim3(256), 0, stream>>>(
            rays_d, pts, times, deltas, bg, gspace, gtime, feat,
            W1, b1, W2, b2, Wc1, bc1, Wc2, bc2, ridx, (float*)d_out);
    }
}

// Round 3
// 429.471 us; speedup vs baseline: 1.8932x; 1.2129x over previous
//
#include <hip/hip_runtime.h>
#include <hip/hip_fp16.h>
#include <math.h>

#define RR 128          // spatial resolution (grid_space + features)
#define TT 150          // time resolution
#define NCH 48          // RANK*OUT_DIM*TIME_RANK
#define NF 32           // feature channels

__device__ __forceinline__ float4 ld4(const float* p) {
    return *reinterpret_cast<const float4*>(p);
}
// load 8 contiguous halves (16B) -> 8 floats
__device__ __forceinline__ void h8ld(const __half* p, float f[8]) {
    uint4 u = *reinterpret_cast<const uint4*>(p);
    float2 x;
    x = __half22float2(__builtin_bit_cast(__half2, u.x)); f[0] = x.x; f[1] = x.y;
    x = __half22float2(__builtin_bit_cast(__half2, u.y)); f[2] = x.x; f[3] = x.y;
    x = __half22float2(__builtin_bit_cast(__half2, u.z)); f[4] = x.x; f[5] = x.y;
    x = __half22float2(__builtin_bit_cast(__half2, u.w)); f[6] = x.x; f[7] = x.y;
}
__device__ __forceinline__ uint h2pack(float a, float b) {
    __half2 h = __halves2half2(__float2half_rn(a), __float2half_rn(b));
    return __builtin_bit_cast(uint, h);
}

// ---- transpose+cast features [32][V] f32 -> [V][32] f16, V = 128^3 ----
__global__ __launch_bounds__(256) void tfeat_h(const float* __restrict__ in,
                                               uint* __restrict__ out) { // out = half2 words
    __shared__ float lds[32][65];
    const int t = threadIdx.x;
    const size_t V = (size_t)RR * RR * RR;
    const size_t v0 = (size_t)blockIdx.x * 64;
    #pragma unroll
    for (int k = 0; k < 8; k++) {
        int idx = k * 256 + t; int c = idx >> 6; int vv = idx & 63;
        lds[c][vv] = in[(size_t)c * V + v0 + vv];
    }
    __syncthreads();
    #pragma unroll
    for (int k = 0; k < 4; k++) {
        int idx = k * 256 + t; int vv = idx >> 4; int cp = idx & 15;
        out[(v0 + vv) * 16 + cp] = h2pack(lds[2 * cp][vv], lds[2 * cp + 1][vv]);
    }
}

// ---- transpose+cast grid_space [3][48][16384] f32 -> [3][16384][48] f16 ----
__global__ __launch_bounds__(256) void tgsp_h(const float* __restrict__ in,
                                              uint* __restrict__ out) { // half2 words
    __shared__ float lds[48][65];
    const int t = threadIdx.x;
    const int p = blockIdx.x >> 8;          // plane
    const int tile = blockIdx.x & 255;
    const size_t V = (size_t)RR * RR;       // 16384
    const size_t v0 = (size_t)tile * 64;
    const float* ip = in + (size_t)p * NCH * V;
    uint* op = out + (size_t)p * V * (NCH / 2);
    #pragma unroll
    for (int k = 0; k < 12; k++) {
        int idx = k * 256 + t; int c = idx >> 6; int vv = idx & 63;
        lds[c][vv] = ip[(size_t)c * V + v0 + vv];
    }
    __syncthreads();
    #pragma unroll
    for (int k = 0; k < 6; k++) {
        int idx = k * 256 + t; int vv = idx / 24; int cp = idx - vv * 24;
        op[(v0 + vv) * 24 + cp] = h2pack(lds[2 * cp][vv], lds[2 * cp + 1][vv]);
    }
}

// ---- main kernel: 2 rays per block (256 threads = 4 waves) ----
// TR=true: gspace [3][R][R][48] f16, feat [R][R][R][32] f16 (transposed+cast)
template<bool TR>
__global__ __launch_bounds__(256, 6) void lrv_main(
    const float* __restrict__ rays_d,
    const float* __restrict__ pts,
    const float* __restrict__ times,
    const float* __restrict__ deltas,
    const float* __restrict__ bg,
    const void* __restrict__ gspace_p,
    const float* __restrict__ gtime,    // [12][TT] original layout
    const void* __restrict__ feat_p,
    const float* __restrict__ W1, const float* __restrict__ b1,
    const float* __restrict__ W2, const float* __restrict__ b2,
    const float* __restrict__ Wc1, const float* __restrict__ bc1,
    const float* __restrict__ Wc2, const float* __restrict__ bc2,
    const int*  __restrict__ ridx,
    float* __restrict__ out)
{
    __shared__ __align__(16) float4 sW1v[35 * 16];   // [i][j/4]
    __shared__ __align__(16) float4 sW2v[64 * 4];    // [j][k/4]
    __shared__ __align__(16) float4 sWc1v[18 * 16];  // [i][j/4]
    __shared__ __align__(16) float  sWc2[64 * 3];
    __shared__ float sb1[64], sbc1[64], sb2[16], sbc2[4];
    __shared__ float sGT[12 * TT];
    __shared__ float waveTot[4];
    __shared__ float4 rbuf[4];

    const int tid  = threadIdx.x;
    const int lane = tid & 63;
    const int wv   = tid >> 6;          // wave in block, 0..3

    {
        float* w1 = (float*)sW1v;
        for (int k = tid; k < 35 * 64; k += 256) w1[k] = W1[k];
        float* w2 = (float*)sW2v;
        for (int k = tid; k < 64 * 16; k += 256) w2[k] = W2[k];
        float* wc1 = (float*)sWc1v;
        for (int k = tid; k < 18 * 64; k += 256) wc1[k] = Wc1[k];
        for (int k = tid; k < 64 * 3; k += 256) sWc2[k] = Wc2[k];
        if (tid < 64) { sb1[tid] = b1[tid]; sbc1[tid] = bc1[tid]; }
        if (tid < 16) sb2[tid] = b2[tid];
        if (tid < 3)  sbc2[tid] = bc2[tid];
        for (int k = tid; k < 12 * TT; k += 256) sGT[k] = gtime[k];
    }
    __syncthreads();

    const int ray = blockIdx.x * 2 + (tid >> 7);
    const int i   = ray * 128 + (tid & 127);

    // ---- 1D time grid sample -> itv[12] ----
    float itv[12];
    {
        float t = times[i];
        float x = (t + 1.f) * 0.5f * (float)(TT - 1);
        x = fminf(fmaxf(x, 0.f), (float)(TT - 1));
        int ti0 = (int)floorf(x);
        ti0 = min(max(ti0, 0), TT - 2);
        float tw = x - (float)ti0;
        #pragma unroll
        for (int c = 0; c < 12; c++) {
            float v0 = sGT[c * TT + ti0];
            float v1 = sGT[c * TT + ti0 + 1];
            itv[c] = v0 * (1.f - tw) + v1 * tw;
        }
    }

    // ---- 3 plane bilinear samples, low-rank contraction ----
    float p0 = pts[i * 3 + 0], p1 = pts[i * 3 + 1], p2 = pts[i * 3 + 2];
    int   pbia[3], pbib[3];
    float pw[3][4];
    {
        const float pa[3] = { p0, p0, p1 };
        const float pb[3] = { p1, p2, p2 };
        #pragma unroll
        for (int c = 0; c < 3; c++) {
            float xa = fminf(fmaxf((pa[c] + 1.f) * 0.5f * (float)(RR - 1), 0.f), (float)(RR - 1));
            float xb = fminf(fmaxf((pb[c] + 1.f) * 0.5f * (float)(RR - 1), 0.f), (float)(RR - 1));
            int ia = min(max((int)floorf(xa), 0), RR - 2);
            int ib = min(max((int)floorf(xb), 0), RR - 2);
            float wa = xa - (float)ia, wb = xb - (float)ib;
            pbia[c] = ia; pbib[c] = ib;
            pw[c][0] = (1.f - wa) * (1.f - wb);
            pw[c][1] = (1.f - wa) * wb;
            pw[c][2] = wa * (1.f - wb);
            pw[c][3] = wa * wb;
        }
    }
    float S12[12];
    if constexpr (TR) {
        const __half* gs = (const __half*)gspace_p;
        size_t b[3][4];
        #pragma unroll
        for (int c = 0; c < 3; c++) {
            size_t b00 = (size_t)c * (RR * RR * NCH)
                       + ((size_t)pbia[c] * RR + pbib[c]) * NCH;
            b[c][0] = b00; b[c][1] = b00 + NCH;
            b[c][2] = b00 + (size_t)RR * NCH; b[c][3] = b00 + (size_t)RR * NCH + NCH;
        }
        #pragma unroll 2
        for (int cb = 0; cb < 6; cb++) {       // 8 channels at a time
            float pr[8];
            #pragma unroll
            for (int p = 0; p < 3; p++) {
                float a[8];
                #pragma unroll
                for (int j = 0; j < 8; j++) a[j] = 0.f;
                #pragma unroll
                for (int corner = 0; corner < 4; corner++) {
                    float t8[8];
                    h8ld(gs + b[p][corner] + cb * 8, t8);
                    float wc = pw[p][corner];
                    #pragma unroll
                    for (int j = 0; j < 8; j++) a[j] = fmaf(wc, t8[j], a[j]);
                }
                #pragma unroll
                for (int j = 0; j < 8; j++) pr[j] = (p == 0) ? a[j] : pr[j] * a[j];
            }
            S12[cb * 2 + 0] = pr[0] + pr[1] + pr[2] + pr[3];
            S12[cb * 2 + 1] = pr[4] + pr[5] + pr[6] + pr[7];
        }
    } else {
        const float* gs = (const float*)gspace_p;
        #pragma unroll
        for (int k = 0; k < 12; k++) S12[k] = 0.f;
        #pragma unroll 4
        for (int ch = 0; ch < NCH; ch++) {
            float prod = 1.f;
            #pragma unroll
            for (int c = 0; c < 3; c++) {
                const float* g = gs + (size_t)(c * NCH + ch) * (RR * RR)
                               + pbia[c] * RR + pbib[c];
                float v = pw[c][0] * g[0] + pw[c][1] * g[1]
                        + pw[c][2] * g[RR] + pw[c][3] * g[RR + 1];
                prod *= v;
            }
            S12[ch >> 2] += prod;
        }
    }
    float cc[3];
    #pragma unroll
    for (int o = 0; o < 3; o++) {
        float a = 0.f;
        #pragma unroll
        for (int t = 0; t < 4; t++) a += S12[o * 4 + t] * itv[o * 4 + t];
        cc[o] = fminf(fmaxf(a, -1.f), 1.f);
    }

    // ---- 3D feature trilinear sample ----
    float in35[36];
    {
        int   fi[3];
        float fw[3];
        #pragma unroll
        for (int k = 0; k < 3; k++) {
            float xk = fminf(fmaxf((cc[k] + 1.f) * 0.5f * (float)(RR - 1), 0.f), (float)(RR - 1));
            int ik = min(max((int)floorf(xk), 0), RR - 2);
            fi[k] = ik; fw[k] = xk - (float)ik;
        }
        float w0 = fw[0], w1 = fw[1], w2 = fw[2];
        float cw[8];
        cw[0] = (1.f - w0) * (1.f - w1) * (1.f - w2);
        cw[1] = (1.f - w0) * (1.f - w1) * w2;
        cw[2] = (1.f - w0) * w1 * (1.f - w2);
        cw[3] = (1.f - w0) * w1 * w2;
        cw[4] = w0 * (1.f - w1) * (1.f - w2);
        cw[5] = w0 * (1.f - w1) * w2;
        cw[6] = w0 * w1 * (1.f - w2);
        cw[7] = w0 * w1 * w2;
        if constexpr (TR) {
            const __half* ft = (const __half*)feat_p;
            #pragma unroll
            for (int q = 0; q < 32; q++) in35[q] = 0.f;
            const size_t oz = NF, oy = (size_t)RR * NF, ox = (size_t)RR * RR * NF;
            const size_t fb = (((size_t)fi[0] * RR + fi[1]) * RR + fi[2]) * NF;
            const size_t coff[8] = { 0, oz, oy, oy + oz, ox, ox + oz, ox + oy, ox + oy + oz };
            #pragma unroll
            for (int corner = 0; corner < 8; corner++) {
                const __half* fp = ft + fb + coff[corner];
                const float s = cw[corner];
                #pragma unroll
                for (int q = 0; q < 4; q++) {
                    float t8[8];
                    h8ld(fp + q * 8, t8);
                    #pragma unroll
                    for (int j = 0; j < 8; j++)
                        in35[q * 8 + j] = fmaf(s, t8[j], in35[q * 8 + j]);
                }
            }
        } else {
            const float* ft = (const float*)feat_p;
            size_t fb = ((size_t)fi[0] * RR + fi[1]) * RR + fi[2];
            #pragma unroll 4
            for (int ch = 0; ch < NF; ch++) {
                const float* f = ft + (size_t)ch * (RR * RR * RR) + fb;
                in35[ch] = cw[0] * f[0]            + cw[1] * f[1]
                         + cw[2] * f[RR]           + cw[3] * f[RR + 1]
                         + cw[4] * f[RR * RR]      + cw[5] * f[RR * RR + 1]
                         + cw[6] * f[RR * RR + RR] + cw[7] * f[RR * RR + RR + 1];
            }
        }
    }
    // ray direction (normalized)
    {
        int r = ridx[i];
        float d0 = rays_d[r * 3 + 0], d1 = rays_d[r * 3 + 1], d2 = rays_d[r * 3 + 2];
        float inv = 1.f / sqrtf(d0 * d0 + d1 * d1 + d2 * d2);
        in35[32] = d0 * inv; in35[33] = d1 * inv; in35[34] = d2 * inv;
    }

    // ---- MLP: (35 -> 64 relu -> 16), fused ----
    float sacc[16];
    #pragma unroll
    for (int k = 0; k < 16; k++) sacc[k] = sb2[k];
    #pragma unroll 2
    for (int jb = 0; jb < 16; jb++) {
        float a0 = sb1[jb * 4 + 0], a1 = sb1[jb * 4 + 1];
        float a2 = sb1[jb * 4 + 2], a3 = sb1[jb * 4 + 3];
        #pragma unroll
        for (int ii = 0; ii < 35; ii++) {
            float xv = in35[ii];
            float4 wvv = sW1v[ii * 16 + jb];
            a0 = fmaf(xv, wvv.x, a0); a1 = fmaf(xv, wvv.y, a1);
            a2 = fmaf(xv, wvv.z, a2); a3 = fmaf(xv, wvv.w, a3);
        }
        a0 = fmaxf(a0, 0.f); a1 = fmaxf(a1, 0.f);
        a2 = fmaxf(a2, 0.f); a3 = fmaxf(a3, 0.f);
        #pragma unroll
        for (int kg = 0; kg < 4; kg++) {
            float4 r0 = sW2v[(jb * 4 + 0) * 4 + kg];
            float4 r1 = sW2v[(jb * 4 + 1) * 4 + kg];
            float4 r2 = sW2v[(jb * 4 + 2) * 4 + kg];
            float4 r3 = sW2v[(jb * 4 + 3) * 4 + kg];
            sacc[kg * 4 + 0] += a0 * r0.x + a1 * r1.x + a2 * r2.x + a3 * r3.x;
            sacc[kg * 4 + 1] += a0 * r0.y + a1 * r1.y + a2 * r2.y + a3 * r3.y;
            sacc[kg * 4 + 2] += a0 * r0.z + a1 * r1.z + a2 * r2.z + a3 * r3.z;
            sacc[kg * 4 + 3] += a0 * r0.w + a1 * r1.w + a2 * r2.w + a3 * r3.w;
        }
    }
    float sigma = expf(fminf(fmaxf(sacc[0], -15.f), 15.f));

    // ---- color MLP: (15+3 -> 64 relu -> 3), fused ----
    float in18[18];
    #pragma unroll
    for (int k = 0; k < 15; k++) in18[k] = sacc[k + 1];
    in18[15] = in35[32]; in18[16] = in35[33]; in18[17] = in35[34];
    float rc0 = sbc2[0], rc1 = sbc2[1], rc2 = sbc2[2];
    #pragma unroll 2
    for (int jb = 0; jb < 16; jb++) {
        float a0 = sbc1[jb * 4 + 0], a1 = sbc1[jb * 4 + 1];
        float a2 = sbc1[jb * 4 + 2], a3 = sbc1[jb * 4 + 3];
        #pragma unroll
        for (int ii = 0; ii < 18; ii++) {
            float xv = in18[ii];
            float4 wvv = sWc1v[ii * 16 + jb];
            a0 = fmaf(xv, wvv.x, a0); a1 = fmaf(xv, wvv.y, a1);
            a2 = fmaf(xv, wvv.z, a2); a3 = fmaf(xv, wvv.w, a3);
        }
        a0 = fmaxf(a0, 0.f); a1 = fmaxf(a1, 0.f);
        a2 = fmaxf(a2, 0.f); a3 = fmaxf(a3, 0.f);
        rc0 += a0 * sWc2[(jb * 4 + 0) * 3 + 0] + a1 * sWc2[(jb * 4 + 1) * 3 + 0]
             + a2 * sWc2[(jb * 4 + 2) * 3 + 0] + a3 * sWc2[(jb * 4 + 3) * 3 + 0];
        rc1 += a0 * sWc2[(jb * 4 + 0) * 3 + 1] + a1 * sWc2[(jb * 4 + 1) * 3 + 1]
             + a2 * sWc2[(jb * 4 + 2) * 3 + 1] + a3 * sWc2[(jb * 4 + 3) * 3 + 1];
        rc2 += a0 * sWc2[(jb * 4 + 0) * 3 + 2] + a1 * sWc2[(jb * 4 + 1) * 3 + 2]
             + a2 * sWc2[(jb * 4 + 2) * 3 + 2] + a3 * sWc2[(jb * 4 + 3) * 3 + 2];
    }
    float r_ = 1.f / (1.f + expf(-rc0));
    float g_ = 1.f / (1.f + expf(-rc1));
    float b_ = 1.f / (1.f + expf(-rc2));

    // ---- per-ray compositing: exclusive scan of tau over 128 samples ----
    float tau = sigma * deltas[i];
    float v = tau;
    #pragma unroll
    for (int off = 1; off < 64; off <<= 1) {
        float u = __shfl_up(v, off, 64);
        if (lane >= off) v += u;
    }
    if (lane == 63) waveTot[wv] = v;
    float excl = v - tau;
    __syncthreads();
    if (wv & 1) excl += waveTot[wv & 2];

    float Tr = expf(-excl);
    float w  = Tr * (1.f - expf(-tau));

    float ax = w * r_, ay = w * g_, az = w * b_, aw = w;
    #pragma unroll
    for (int off = 32; off; off >>= 1) {
        ax += __shfl_down(ax, off, 64);
        ay += __shfl_down(ay, off, 64);
        az += __shfl_down(az, off, 64);
        aw += __shfl_down(aw, off, 64);
    }
    if (lane == 0) rbuf[wv] = make_float4(ax, ay, az, aw);
    __syncthreads();
    if (lane == 0 && (wv & 1) == 0) {
        float cx = rbuf[wv].x + rbuf[wv + 1].x;
        float cy = rbuf[wv].y + rbuf[wv + 1].y;
        float cz = rbuf[wv].z + rbuf[wv + 1].z;
        float alpha = rbuf[wv].w + rbuf[wv + 1].w;
        out[ray * 3 + 0] = cx + (1.f - alpha) * bg[ray * 3 + 0];
        out[ray * 3 + 1] = cy + (1.f - alpha) * bg[ray * 3 + 1];
        out[ray * 3 + 2] = cz + (1.f - alpha) * bg[ray * 3 + 2];
    }
}

extern "C" void kernel_launch(void* const* d_in, const int* in_sizes, int n_in,
                              void* d_out, int out_size, void* d_ws, size_t ws_size,
                              hipStream_t stream) {
    const float* rays_d = (const float*)d_in[0];
    const float* pts    = (const float*)d_in[1];
    const float* times  = (const float*)d_in[2];
    const float* deltas = (const float*)d_in[3];
    const float* bg     = (const float*)d_in[4];
    const float* gspace = (const float*)d_in[5];
    const float* gtime  = (const float*)d_in[6];
    const float* feat   = (const float*)d_in[7];
    const float* W1  = (const float*)d_in[8];
    const float* b1  = (const float*)d_in[9];
    const float* W2  = (const float*)d_in[10];
    const float* b2  = (const float*)d_in[11];
    const float* Wc1 = (const float*)d_in[12];
    const float* bc1 = (const float*)d_in[13];
    const float* Wc2 = (const float*)d_in[14];
    const float* bc2 = (const float*)d_in[15];
    const int*   ridx = (const int*)d_in[16];

    const int n_rays = in_sizes[0] / 3;   // 4096

    const size_t FEAT_HB = (size_t)NF * RR * RR * RR * sizeof(__half);   // 134 MB
    const size_t GSP_HB  = (size_t)3 * NCH * RR * RR * sizeof(__half);   // 4.7 MB

    if (ws_size >= FEAT_HB + GSP_HB) {
        __half* feat_t = (__half*)d_ws;
        __half* gsp_t  = (__half*)((char*)d_ws + FEAT_HB);
        tfeat_h<<<dim3(RR * RR * RR / 64), dim3(256), 0, stream>>>(feat, (uint*)feat_t);
        tgsp_h<<<dim3(3 * 256), dim3(256), 0, stream>>>(gspace, (uint*)gsp_t);
        lrv_main<true><<<dim3(n_rays / 2), dim3(256), 0, stream>>>(
            rays_d, pts, times, deltas, bg, (const void*)gsp_t, gtime, (const void*)feat_t,
            W1, b1, W2, b2, Wc1, bc1, Wc2, bc2, ridx, (float*)d_out);
    } else {
        lrv_main<false><<<dim3(n_rays / 2), dim3(256), 0, stream>>>(
            rays_d, pts, times, deltas, bg, (const void*)gspace, gtime, (const void*)feat,
            W1, b1, W2, b2, Wc1, bc1, Wc2, bc2, ridx, (float*)d_out);
    }
}

// Round 4
// 428.938 us; speedup vs baseline: 1.8956x; 1.0012x over previous
//
#include <hip/hip_runtime.h>
#include <hip/hip_fp16.h>
#include <math.h>

#define RR 128          // spatial resolution (grid_space + features)
#define TT 150          // time resolution
#define NCH 48          // RANK*OUT_DIM*TIME_RANK
#define NF 32           // feature channels

typedef float vf2 __attribute__((ext_vector_type(2)));

__device__ __forceinline__ float4 ld4(const float* p) {
    return *reinterpret_cast<const float4*>(p);
}
// load 8 contiguous halves (16B) -> 8 floats
__device__ __forceinline__ void h8ld(const __half* p, float f[8]) {
    uint4 u = *reinterpret_cast<const uint4*>(p);
    float2 x;
    x = __half22float2(__builtin_bit_cast(__half2, u.x)); f[0] = x.x; f[1] = x.y;
    x = __half22float2(__builtin_bit_cast(__half2, u.y)); f[2] = x.x; f[3] = x.y;
    x = __half22float2(__builtin_bit_cast(__half2, u.z)); f[4] = x.x; f[5] = x.y;
    x = __half22float2(__builtin_bit_cast(__half2, u.w)); f[6] = x.x; f[7] = x.y;
}
__device__ __forceinline__ uint h2pack(float a, float b) {
    __half2 h = __halves2half2(__float2half_rn(a), __float2half_rn(b));
    return __builtin_bit_cast(uint, h);
}
// unpack one uint (4 fp8 e4m3) and fma into a[0..3] with scale s
__device__ __forceinline__ void up4(uint u, float s, float* a) {
    vf2 lo = __builtin_amdgcn_cvt_pk_f32_fp8(u, false);
    vf2 hi = __builtin_amdgcn_cvt_pk_f32_fp8(u, true);
    a[0] = fmaf(s, lo[0], a[0]); a[1] = fmaf(s, lo[1], a[1]);
    a[2] = fmaf(s, hi[0], a[2]); a[3] = fmaf(s, hi[1], a[3]);
}
__device__ __forceinline__ void up16(uint4 q, float s, float* a) {
    up4(q.x, s, a + 0); up4(q.y, s, a + 4);
    up4(q.z, s, a + 8); up4(q.w, s, a + 12);
}

// ---- transpose+cast features [32][V] f32 -> [V][32] fp8 (x16 scale), V=128^3 ----
__global__ __launch_bounds__(256) void tfeat_8(const float* __restrict__ in,
                                               uint* __restrict__ out) { // 4 fp8 per word
    __shared__ float lds[32][65];
    const int t = threadIdx.x;
    const size_t V = (size_t)RR * RR * RR;
    const size_t v0 = (size_t)blockIdx.x * 64;
    #pragma unroll
    for (int k = 0; k < 8; k++) {
        int idx = k * 256 + t; int c = idx >> 6; int vv = idx & 63;
        lds[c][vv] = in[(size_t)c * V + v0 + vv];
    }
    __syncthreads();
    #pragma unroll
    for (int k = 0; k < 2; k++) {
        int idx = k * 256 + t; int vv = idx >> 3; int wp = idx & 7;
        float a = lds[4 * wp + 0][vv] * 16.f;
        float b = lds[4 * wp + 1][vv] * 16.f;
        float c = lds[4 * wp + 2][vv] * 16.f;
        float d = lds[4 * wp + 3][vv] * 16.f;
        uint w = (uint)__builtin_amdgcn_cvt_pk_fp8_f32(a, b, 0, false);
        w = (uint)__builtin_amdgcn_cvt_pk_fp8_f32(c, d, w, true);
        out[(v0 + vv) * 8 + wp] = w;
    }
}

// ---- transpose+cast grid_space [3][48][16384] f32 -> [3][16384][48] f16 ----
__global__ __launch_bounds__(256) void tgsp_h(const float* __restrict__ in,
                                              uint* __restrict__ out) { // half2 words
    __shared__ float lds[48][65];
    const int t = threadIdx.x;
    const int p = blockIdx.x >> 8;          // plane
    const int tile = blockIdx.x & 255;
    const size_t V = (size_t)RR * RR;       // 16384
    const size_t v0 = (size_t)tile * 64;
    const float* ip = in + (size_t)p * NCH * V;
    uint* op = out + (size_t)p * V * (NCH / 2);
    #pragma unroll
    for (int k = 0; k < 12; k++) {
        int idx = k * 256 + t; int c = idx >> 6; int vv = idx & 63;
        lds[c][vv] = ip[(size_t)c * V + v0 + vv];
    }
    __syncthreads();
    #pragma unroll
    for (int k = 0; k < 6; k++) {
        int idx = k * 256 + t; int vv = idx / 24; int cp = idx - vv * 24;
        op[(v0 + vv) * 24 + cp] = h2pack(lds[2 * cp][vv], lds[2 * cp + 1][vv]);
    }
}

// ---- main kernel: 2 rays per block (256 threads = 4 waves) ----
// TR=true: gspace [3][R][R][48] f16, feat [R][R][R][32] fp8 (x16)
template<bool TR>
__global__ __launch_bounds__(256, 6) void lrv_main(
    const float* __restrict__ rays_d,
    const float* __restrict__ pts,
    const float* __restrict__ times,
    const float* __restrict__ deltas,
    const float* __restrict__ bg,
    const void* __restrict__ gspace_p,
    const float* __restrict__ gtime,    // [12][TT] original layout
    const void* __restrict__ feat_p,
    const float* __restrict__ W1, const float* __restrict__ b1,
    const float* __restrict__ W2, const float* __restrict__ b2,
    const float* __restrict__ Wc1, const float* __restrict__ bc1,
    const float* __restrict__ Wc2, const float* __restrict__ bc2,
    const int*  __restrict__ ridx,
    float* __restrict__ out)
{
    __shared__ __align__(16) float4 sW1v[35 * 16];   // [i][j/4]
    __shared__ __align__(16) float4 sW2v[64 * 4];    // [j][k/4]
    __shared__ __align__(16) float4 sWc1v[18 * 16];  // [i][j/4]
    __shared__ __align__(16) float  sWc2[64 * 3];
    __shared__ float sb1[64], sbc1[64], sb2[16], sbc2[4];
    __shared__ float sGT[12 * TT];
    __shared__ float waveTot[4];
    __shared__ float4 rbuf[4];

    const int tid  = threadIdx.x;
    const int lane = tid & 63;
    const int wv   = tid >> 6;          // wave in block, 0..3

    {
        float* w1 = (float*)sW1v;
        for (int k = tid; k < 35 * 64; k += 256) w1[k] = W1[k];
        float* w2 = (float*)sW2v;
        for (int k = tid; k < 64 * 16; k += 256) w2[k] = W2[k];
        float* wc1 = (float*)sWc1v;
        for (int k = tid; k < 18 * 64; k += 256) wc1[k] = Wc1[k];
        for (int k = tid; k < 64 * 3; k += 256) sWc2[k] = Wc2[k];
        if (tid < 64) { sb1[tid] = b1[tid]; sbc1[tid] = bc1[tid]; }
        if (tid < 16) sb2[tid] = b2[tid];
        if (tid < 3)  sbc2[tid] = bc2[tid];
        for (int k = tid; k < 12 * TT; k += 256) sGT[k] = gtime[k];
    }
    __syncthreads();

    const int ray = blockIdx.x * 2 + (tid >> 7);
    const int i   = ray * 128 + (tid & 127);

    // ---- 1D time grid sample -> itv[12] ----
    float itv[12];
    {
        float t = times[i];
        float x = (t + 1.f) * 0.5f * (float)(TT - 1);
        x = fminf(fmaxf(x, 0.f), (float)(TT - 1));
        int ti0 = (int)floorf(x);
        ti0 = min(max(ti0, 0), TT - 2);
        float tw = x - (float)ti0;
        #pragma unroll
        for (int c = 0; c < 12; c++) {
            float v0 = sGT[c * TT + ti0];
            float v1 = sGT[c * TT + ti0 + 1];
            itv[c] = v0 * (1.f - tw) + v1 * tw;
        }
    }

    // ---- 3 plane bilinear samples, low-rank contraction ----
    float p0 = pts[i * 3 + 0], p1 = pts[i * 3 + 1], p2 = pts[i * 3 + 2];
    int   pbia[3], pbib[3];
    float pw[3][4];
    {
        const float pa[3] = { p0, p0, p1 };
        const float pb[3] = { p1, p2, p2 };
        #pragma unroll
        for (int c = 0; c < 3; c++) {
            float xa = fminf(fmaxf((pa[c] + 1.f) * 0.5f * (float)(RR - 1), 0.f), (float)(RR - 1));
            float xb = fminf(fmaxf((pb[c] + 1.f) * 0.5f * (float)(RR - 1), 0.f), (float)(RR - 1));
            int ia = min(max((int)floorf(xa), 0), RR - 2);
            int ib = min(max((int)floorf(xb), 0), RR - 2);
            float wa = xa - (float)ia, wb = xb - (float)ib;
            pbia[c] = ia; pbib[c] = ib;
            pw[c][0] = (1.f - wa) * (1.f - wb);
            pw[c][1] = (1.f - wa) * wb;
            pw[c][2] = wa * (1.f - wb);
            pw[c][3] = wa * wb;
        }
    }
    float S12[12];
    if constexpr (TR) {
        const __half* gs = (const __half*)gspace_p;
        size_t b[3][4];
        #pragma unroll
        for (int c = 0; c < 3; c++) {
            size_t b00 = (size_t)c * (RR * RR * NCH)
                       + ((size_t)pbia[c] * RR + pbib[c]) * NCH;
            b[c][0] = b00; b[c][1] = b00 + NCH;
            b[c][2] = b00 + (size_t)RR * NCH; b[c][3] = b00 + (size_t)RR * NCH + NCH;
        }
        #pragma unroll 2
        for (int cb = 0; cb < 6; cb++) {       // 8 channels at a time
            float pr[8];
            #pragma unroll
            for (int p = 0; p < 3; p++) {
                float a[8];
                #pragma unroll
                for (int j = 0; j < 8; j++) a[j] = 0.f;
                #pragma unroll
                for (int corner = 0; corner < 4; corner++) {
                    float t8[8];
                    h8ld(gs + b[p][corner] + cb * 8, t8);
                    float wc = pw[p][corner];
                    #pragma unroll
                    for (int j = 0; j < 8; j++) a[j] = fmaf(wc, t8[j], a[j]);
                }
                #pragma unroll
                for (int j = 0; j < 8; j++) pr[j] = (p == 0) ? a[j] : pr[j] * a[j];
            }
            S12[cb * 2 + 0] = pr[0] + pr[1] + pr[2] + pr[3];
            S12[cb * 2 + 1] = pr[4] + pr[5] + pr[6] + pr[7];
        }
    } else {
        const float* gs = (const float*)gspace_p;
        #pragma unroll
        for (int k = 0; k < 12; k++) S12[k] = 0.f;
        #pragma unroll 4
        for (int ch = 0; ch < NCH; ch++) {
            float prod = 1.f;
            #pragma unroll
            for (int c = 0; c < 3; c++) {
                const float* g = gs + (size_t)(c * NCH + ch) * (RR * RR)
                               + pbia[c] * RR + pbib[c];
                float v = pw[c][0] * g[0] + pw[c][1] * g[1]
                        + pw[c][2] * g[RR] + pw[c][3] * g[RR + 1];
                prod *= v;
            }
            S12[ch >> 2] += prod;
        }
    }
    float cc[3];
    #pragma unroll
    for (int o = 0; o < 3; o++) {
        float a = 0.f;
        #pragma unroll
        for (int t = 0; t < 4; t++) a += S12[o * 4 + t] * itv[o * 4 + t];
        cc[o] = fminf(fmaxf(a, -1.f), 1.f);
    }

    // ---- 3D feature trilinear sample ----
    float in35[36];
    {
        int   fi[3];
        float fw[3];
        #pragma unroll
        for (int k = 0; k < 3; k++) {
            float xk = fminf(fmaxf((cc[k] + 1.f) * 0.5f * (float)(RR - 1), 0.f), (float)(RR - 1));
            int ik = min(max((int)floorf(xk), 0), RR - 2);
            fi[k] = ik; fw[k] = xk - (float)ik;
        }
        float w0 = fw[0], w1 = fw[1], w2 = fw[2];
        float cw[8];
        cw[0] = (1.f - w0) * (1.f - w1) * (1.f - w2);
        cw[1] = (1.f - w0) * (1.f - w1) * w2;
        cw[2] = (1.f - w0) * w1 * (1.f - w2);
        cw[3] = (1.f - w0) * w1 * w2;
        cw[4] = w0 * (1.f - w1) * (1.f - w2);
        cw[5] = w0 * (1.f - w1) * w2;
        cw[6] = w0 * w1 * (1.f - w2);
        cw[7] = w0 * w1 * w2;
        if constexpr (TR) {
            // feat: [RR][RR][RR][32] fp8 (x16). voxel = 8 words; z-pair = 16 words = 64B
            const uint* f8 = (const uint*)feat_p;
            #pragma unroll
            for (int q = 0; q < 32; q++) in35[q] = 0.f;
            const size_t oy = (size_t)RR * 8, ox = (size_t)RR * RR * 8;
            const size_t fb = (((size_t)fi[0] * RR + fi[1]) * RR + fi[2]) * 8;
            const size_t cxy[4] = { fb, fb + oy, fb + ox, fb + ox + oy };
            #pragma unroll
            for (int j = 0; j < 4; j++) {
                const uint4* p = reinterpret_cast<const uint4*>(f8 + cxy[j]);
                uint4 q0 = p[0], q1 = p[1];   // z0: ch 0..15, 16..31
                uint4 q2 = p[2], q3 = p[3];   // z1: ch 0..15, 16..31
                float s0 = cw[2 * j + 0] * 0.0625f;
                float s1 = cw[2 * j + 1] * 0.0625f;
                up16(q0, s0, in35 + 0);
                up16(q1, s0, in35 + 16);
                up16(q2, s1, in35 + 0);
                up16(q3, s1, in35 + 16);
            }
        } else {
            const float* ft = (const float*)feat_p;
            size_t fb = ((size_t)fi[0] * RR + fi[1]) * RR + fi[2];
            #pragma unroll 4
            for (int ch = 0; ch < NF; ch++) {
                const float* f = ft + (size_t)ch * (RR * RR * RR) + fb;
                in35[ch] = cw[0] * f[0]            + cw[1] * f[1]
                         + cw[2] * f[RR]           + cw[3] * f[RR + 1]
                         + cw[4] * f[RR * RR]      + cw[5] * f[RR * RR + 1]
                         + cw[6] * f[RR * RR + RR] + cw[7] * f[RR * RR + RR + 1];
            }
        }
    }
    // ray direction (normalized)
    {
        int r = ridx[i];
        float d0 = rays_d[r * 3 + 0], d1 = rays_d[r * 3 + 1], d2 = rays_d[r * 3 + 2];
        float inv = 1.f / sqrtf(d0 * d0 + d1 * d1 + d2 * d2);
        in35[32] = d0 * inv; in35[33] = d1 * inv; in35[34] = d2 * inv;
    }

    // ---- MLP: (35 -> 64 relu -> 16), fused ----
    float sacc[16];
    #pragma unroll
    for (int k = 0; k < 16; k++) sacc[k] = sb2[k];
    #pragma unroll 2
    for (int jb = 0; jb < 16; jb++) {
        float a0 = sb1[jb * 4 + 0], a1 = sb1[jb * 4 + 1];
        float a2 = sb1[jb * 4 + 2], a3 = sb1[jb * 4 + 3];
        #pragma unroll
        for (int ii = 0; ii < 35; ii++) {
            float xv = in35[ii];
            float4 wvv = sW1v[ii * 16 + jb];
            a0 = fmaf(xv, wvv.x, a0); a1 = fmaf(xv, wvv.y, a1);
            a2 = fmaf(xv, wvv.z, a2); a3 = fmaf(xv, wvv.w, a3);
        }
        a0 = fmaxf(a0, 0.f); a1 = fmaxf(a1, 0.f);
        a2 = fmaxf(a2, 0.f); a3 = fmaxf(a3, 0.f);
        #pragma unroll
        for (int kg = 0; kg < 4; kg++) {
            float4 r0 = sW2v[(jb * 4 + 0) * 4 + kg];
            float4 r1 = sW2v[(jb * 4 + 1) * 4 + kg];
            float4 r2 = sW2v[(jb * 4 + 2) * 4 + kg];
            float4 r3 = sW2v[(jb * 4 + 3) * 4 + kg];
            sacc[kg * 4 + 0] += a0 * r0.x + a1 * r1.x + a2 * r2.x + a3 * r3.x;
            sacc[kg * 4 + 1] += a0 * r0.y + a1 * r1.y + a2 * r2.y + a3 * r3.y;
            sacc[kg * 4 + 2] += a0 * r0.z + a1 * r1.z + a2 * r2.z + a3 * r3.z;
            sacc[kg * 4 + 3] += a0 * r0.w + a1 * r1.w + a2 * r2.w + a3 * r3.w;
        }
    }
    float sigma = expf(fminf(fmaxf(sacc[0], -15.f), 15.f));

    // ---- color MLP: (15+3 -> 64 relu -> 3), fused ----
    float in18[18];
    #pragma unroll
    for (int k = 0; k < 15; k++) in18[k] = sacc[k + 1];
    in18[15] = in35[32]; in18[16] = in35[33]; in18[17] = in35[34];
    float rc0 = sbc2[0], rc1 = sbc2[1], rc2 = sbc2[2];
    #pragma unroll 2
    for (int jb = 0; jb < 16; jb++) {
        float a0 = sbc1[jb * 4 + 0], a1 = sbc1[jb * 4 + 1];
        float a2 = sbc1[jb * 4 + 2], a3 = sbc1[jb * 4 + 3];
        #pragma unroll
        for (int ii = 0; ii < 18; ii++) {
            float xv = in18[ii];
            float4 wvv = sWc1v[ii * 16 + jb];
            a0 = fmaf(xv, wvv.x, a0); a1 = fmaf(xv, wvv.y, a1);
            a2 = fmaf(xv, wvv.z, a2); a3 = fmaf(xv, wvv.w, a3);
        }
        a0 = fmaxf(a0, 0.f); a1 = fmaxf(a1, 0.f);
        a2 = fmaxf(a2, 0.f); a3 = fmaxf(a3, 0.f);
        rc0 += a0 * sWc2[(jb * 4 + 0) * 3 + 0] + a1 * sWc2[(jb * 4 + 1) * 3 + 0]
             + a2 * sWc2[(jb * 4 + 2) * 3 + 0] + a3 * sWc2[(jb * 4 + 3) * 3 + 0];
        rc1 += a0 * sWc2[(jb * 4 + 0) * 3 + 1] + a1 * sWc2[(jb * 4 + 1) * 3 + 1]
             + a2 * sWc2[(jb * 4 + 2) * 3 + 1] + a3 * sWc2[(jb * 4 + 3) * 3 + 1];
        rc2 += a0 * sWc2[(jb * 4 + 0) * 3 + 2] + a1 * sWc2[(jb * 4 + 1) * 3 + 2]
             + a2 * sWc2[(jb * 4 + 2) * 3 + 2] + a3 * sWc2[(jb * 4 + 3) * 3 + 2];
    }
    float r_ = 1.f / (1.f + expf(-rc0));
    float g_ = 1.f / (1.f + expf(-rc1));
    float b_ = 1.f / (1.f + expf(-rc2));

    // ---- per-ray compositing: exclusive scan of tau over 128 samples ----
    float tau = sigma * deltas[i];
    float v = tau;
    #pragma unroll
    for (int off = 1; off < 64; off <<= 1) {
        float u = __shfl_up(v, off, 64);
        if (lane >= off) v += u;
    }
    if (lane == 63) waveTot[wv] = v;
    float excl = v - tau;
    __syncthreads();
    if (wv & 1) excl += waveTot[wv & 2];

    float Tr = expf(-excl);
    float w  = Tr * (1.f - expf(-tau));

    float ax = w * r_, ay = w * g_, az = w * b_, aw = w;
    #pragma unroll
    for (int off = 32; off; off >>= 1) {
        ax += __shfl_down(ax, off, 64);
        ay += __shfl_down(ay, off, 64);
        az += __shfl_down(az, off, 64);
        aw += __shfl_down(aw, off, 64);
    }
    if (lane == 0) rbuf[wv] = make_float4(ax, ay, az, aw);
    __syncthreads();
    if (lane == 0 && (wv & 1) == 0) {
        float cx = rbuf[wv].x + rbuf[wv + 1].x;
        float cy = rbuf[wv].y + rbuf[wv + 1].y;
        float cz = rbuf[wv].z + rbuf[wv + 1].z;
        float alpha = rbuf[wv].w + rbuf[wv + 1].w;
        out[ray * 3 + 0] = cx + (1.f - alpha) * bg[ray * 3 + 0];
        out[ray * 3 + 1] = cy + (1.f - alpha) * bg[ray * 3 + 1];
        out[ray * 3 + 2] = cz + (1.f - alpha) * bg[ray * 3 + 2];
    }
}

extern "C" void kernel_launch(void* const* d_in, const int* in_sizes, int n_in,
                              void* d_out, int out_size, void* d_ws, size_t ws_size,
                              hipStream_t stream) {
    const float* rays_d = (const float*)d_in[0];
    const float* pts    = (const float*)d_in[1];
    const float* times  = (const float*)d_in[2];
    const float* deltas = (const float*)d_in[3];
    const float* bg     = (const float*)d_in[4];
    const float* gspace = (const float*)d_in[5];
    const float* gtime  = (const float*)d_in[6];
    const float* feat   = (const float*)d_in[7];
    const float* W1  = (const float*)d_in[8];
    const float* b1  = (const float*)d_in[9];
    const float* W2  = (const float*)d_in[10];
    const float* b2  = (const float*)d_in[11];
    const float* Wc1 = (const float*)d_in[12];
    const float* bc1 = (const float*)d_in[13];
    const float* Wc2 = (const float*)d_in[14];
    const float* bc2 = (const float*)d_in[15];
    const int*   ridx = (const int*)d_in[16];

    const int n_rays = in_sizes[0] / 3;   // 4096

    const size_t FEAT_8B = (size_t)NF * RR * RR * RR;                    // 67 MB (fp8)
    const size_t GSP_HB  = (size_t)3 * NCH * RR * RR * sizeof(__half);   // 4.7 MB

    if (ws_size >= FEAT_8B + GSP_HB) {
        uint*   feat_t = (uint*)d_ws;
        __half* gsp_t  = (__half*)((char*)d_ws + FEAT_8B);
        tfeat_8<<<dim3(RR * RR * RR / 64), dim3(256), 0, stream>>>(feat, feat_t);
        tgsp_h<<<dim3(3 * 256), dim3(256), 0, stream>>>(gspace, (uint*)gsp_t);
        lrv_main<true><<<dim3(n_rays / 2), dim3(256), 0, stream>>>(
            rays_d, pts, times, deltas, bg, (const void*)gsp_t, gtime, (const void*)feat_t,
            W1, b1, W2, b2, Wc1, bc1, Wc2, bc2, ridx, (float*)d_out);
    } else {
        lrv_main<false><<<dim3(n_rays / 2), dim3(256), 0, stream>>>(
            rays_d, pts, times, deltas, bg, (const void*)gspace, gtime, (const void*)feat,
            W1, b1, W2, b2, Wc1, bc1, Wc2, bc2, ridx, (float*)d_out);
    }
}